// Round 11
// baseline (259.512 us; speedup 1.0000x reference)
//
#include <hip/hip_runtime.h>
#include <hip/hip_cooperative_groups.h>
#include <math.h>

namespace cg = cooperative_groups;

// Problem constants
#define B 2
#define N 8192            // points per batch
#define PTS_STRIDE (N*3)
#define VOXEL 0.1f

#define PBLK 1024
#define MBLK 256          // mega kernel: 256 thr = 4 waves
#define MGRID 1024        // exactly 4 blocks/CU on 256 CUs (co-resident)

// ws layout (float offsets); ws_size >= 17 MB known, we use ~3.4 MB.
//  [16] acc   [17] ticket   [20..31] gmin[g][3]
//  OFF_PACK per g=arr*2+b (PERG=147456 floats):
//    AFLO[N] short8: [y0,y1,y2,yyh,yyl,w0,w1,w2]   (A rows, k=0..7)
//    AFHI[N] short8: [vvh,vvl,0,...]               (A rows, k=8..15)
//    BR[N]   short8: [-2x0,-2x1,-2x2,1,1,0,0,0]    (B raw col, k=0..7)
//    BV[N]   short8: [0,0,0,0,0,-2u0,-2u1,-2u2]    (B vox col, k=0..7)
//    XXR[N], XXV[N] f32
//  OFF_PART: float part[ysub(4)][slot(4)][var(2)][x(8192)] = 1 MB, single writer each
#define WS_ACC 16
#define WS_TICKET 17
#define WS_GMIN 20
#define OFF_PACK 32
#define PERG 147456
#define OFF_AFLO(g) (OFF_PACK + (g)*PERG)
#define OFF_AFHI(g) (OFF_AFLO(g) + 32768)
#define OFF_BR(g)   (OFF_AFLO(g) + 65536)
#define OFF_BV(g)   (OFF_AFLO(g) + 98304)
#define OFF_XXR(g)  (OFF_AFLO(g) + 131072)
#define OFF_XXV(g)  (OFF_AFLO(g) + 139264)
#define OFF_PART    (OFF_PACK + 4*PERG)
#define PART_IDX(ys, slot, var, x) (OFF_PART + (((((ys)*4 + (slot))*2 + (var)) << 13)) + (x))

typedef __attribute__((ext_vector_type(8))) short short8;    // 8 bf16 (MFMA A/B frag)
typedef __attribute__((ext_vector_type(16))) float f16v;     // 32x32 MFMA C/D frag

union S8 { short8 v; unsigned short u[8]; };

__device__ __forceinline__ unsigned short f2bf(float f) {    // RNE f32->bf16
    unsigned u = __float_as_uint(f);
    return (unsigned short)((u + 0x7FFFu + ((u >> 16) & 1u)) >> 16);
}
__device__ __forceinline__ float bf2f(unsigned short h) {
    return __uint_as_float(((unsigned)h) << 16);
}
__device__ __forceinline__ float voxq(float v, float g) {
    return (float)(int)((v - g) / VOXEL);   // trunc like .astype(int32)
}

// 4 blocks (one per g), vectorized 3x float4 = 4 points per thread-iter.
__global__ void __launch_bounds__(PBLK)
gmin_kernel(const float* __restrict__ preds,
            const float* __restrict__ gts,
            float* __restrict__ ws) {
    const int g   = blockIdx.x;        // g = arr*2 + b
    const int arr = g >> 1;
    const int b   = g & 1;
    const float4* base4 = (const float4*)((arr ? gts : preds) + b * PTS_STRIDE);

    float m0 = INFINITY, m1 = INFINITY, m2 = INFINITY;
#pragma unroll
    for (int j = 0; j < 2; ++j) {
        const int i = j * PBLK + threadIdx.x;     // 0..2047, 4 points each
        const float4 q0 = base4[i*3+0];   // p0x p0y p0z p1x
        const float4 q1 = base4[i*3+1];   // p1y p1z p2x p2y
        const float4 q2 = base4[i*3+2];   // p2z p3x p3y p3z
        float v;
        v = q0.x; m0 = fminf(m0, (v!=v)?INFINITY:v);
        v = q0.w; m0 = fminf(m0, (v!=v)?INFINITY:v);
        v = q1.z; m0 = fminf(m0, (v!=v)?INFINITY:v);
        v = q2.y; m0 = fminf(m0, (v!=v)?INFINITY:v);
        v = q0.y; m1 = fminf(m1, (v!=v)?INFINITY:v);
        v = q1.x; m1 = fminf(m1, (v!=v)?INFINITY:v);
        v = q1.w; m1 = fminf(m1, (v!=v)?INFINITY:v);
        v = q2.z; m1 = fminf(m1, (v!=v)?INFINITY:v);
        v = q0.z; m2 = fminf(m2, (v!=v)?INFINITY:v);
        v = q1.y; m2 = fminf(m2, (v!=v)?INFINITY:v);
        v = q2.x; m2 = fminf(m2, (v!=v)?INFINITY:v);
        v = q2.w; m2 = fminf(m2, (v!=v)?INFINITY:v);
    }
    for (int off = 32; off; off >>= 1) {
        m0 = fminf(m0, __shfl_down(m0, off));
        m1 = fminf(m1, __shfl_down(m1, off));
        m2 = fminf(m2, __shfl_down(m2, off));
    }
    __shared__ float sm[16][3];
    const int wave = threadIdx.x >> 6, lane = threadIdx.x & 63;
    if (lane == 0) { sm[wave][0] = m0; sm[wave][1] = m1; sm[wave][2] = m2; }
    __syncthreads();
    if (threadIdx.x == 0) {
        float a0 = sm[0][0], a1 = sm[0][1], a2 = sm[0][2];
        for (int w = 1; w < 16; ++w) {
            a0 = fminf(a0, sm[w][0]);
            a1 = fminf(a1, sm[w][1]);
            a2 = fminf(a2, sm[w][2]);
        }
        ws[WS_GMIN + g*3+0] = a0; ws[WS_GMIN + g*3+1] = a1; ws[WS_GMIN + g*3+2] = a2;
        if (g == 0) { ws[WS_ACC] = 0.0f; ((unsigned*)ws)[WS_TICKET] = 0u; }
    }
}

// Cooperative mega-kernel: pack -> grid.sync -> chamfer -> grid.sync -> finalize.
// 1024 blocks x 256 threads (exactly 4 blocks/CU co-resident, VGPR capped 128).
__global__ void __launch_bounds__(MBLK, 4)
mega_kernel(const float* __restrict__ preds,
            const float* __restrict__ gts,
            float* __restrict__ ws,
            float* __restrict__ out) {
    cg::grid_group grid = cg::this_grid();
    const int bid = blockIdx.x;
    const int tid = threadIdx.x;

    // ---------------- Phase A: pack (32 points per block, threads 0..31) ----
    if (tid < 32) {
        const int g   = bid >> 8;                     // uniform per block
        const int idx = (bid & 255) * 32 + tid;       // point within batch
        const int arr = g >> 1;
        const int b   = g & 1;
        const float* base = (arr ? gts : preds) + b * PTS_STRIDE;

        const float g0 = ws[WS_GMIN + g*3+0];
        const float g1 = ws[WS_GMIN + g*3+1];
        const float g2 = ws[WS_GMIN + g*3+2];

        const float p0 = base[idx*3+0], p1 = base[idx*3+1], p2 = base[idx*3+2];
        const float w0 = voxq(p0, g0), w1 = voxq(p1, g1), w2 = voxq(p2, g2);
        const float rr = fmaf(p0,p0, fmaf(p1,p1, p2*p2));
        const float vv = fmaf(w0,w0, fmaf(w1,w1, w2*w2));

        const unsigned short yyh = f2bf(rr);
        const unsigned short yyl = f2bf(rr - bf2f(yyh));
        const unsigned short vvh = f2bf(vv);
        const unsigned short vvl = f2bf(vv - bf2f(vvh));
        const unsigned short ONE = 0x3F80;

        short8* AFLO = (short8*)(ws + OFF_AFLO(g));
        short8* AFHI = (short8*)(ws + OFF_AFHI(g));
        short8* BR   = (short8*)(ws + OFF_BR(g));
        short8* BV   = (short8*)(ws + OFF_BV(g));

        S8 f;
        // A lo (k=0..7): [y0,y1,y2,yyh,yyl, w0,w1,w2]
        f.u[0]=f2bf(p0); f.u[1]=f2bf(p1); f.u[2]=f2bf(p2);
        f.u[3]=yyh; f.u[4]=yyl; f.u[5]=f2bf(w0); f.u[6]=f2bf(w1); f.u[7]=f2bf(w2);
        AFLO[idx] = f.v;
        // A hi (k=8..15): [vvh,vvl,0...]
        f.u[0]=vvh; f.u[1]=vvl; f.u[2]=0; f.u[3]=0; f.u[4]=0; f.u[5]=0; f.u[6]=0; f.u[7]=0;
        AFHI[idx] = f.v;
        // B raw col (k=0..7)
        f.u[0]=f2bf(-2.0f*p0); f.u[1]=f2bf(-2.0f*p1); f.u[2]=f2bf(-2.0f*p2);
        f.u[3]=ONE; f.u[4]=ONE; f.u[5]=0; f.u[6]=0; f.u[7]=0;
        BR[idx] = f.v;
        // B vox col (k=0..7)
        f.u[0]=0; f.u[1]=0; f.u[2]=0; f.u[3]=0; f.u[4]=0;
        f.u[5]=f2bf(-2.0f*w0); f.u[6]=f2bf(-2.0f*w1); f.u[7]=f2bf(-2.0f*w2);
        BV[idx] = f.v;
        ws[OFF_XXR(g) + idx] = rr;
        ws[OFF_XXV(g) + idx] = vv;
    }

    grid.sync();

    // ---------------- Phase B: chamfer (one task per wave, 4096 tasks) ------
    {
        const int wave = tid >> 6, lane = tid & 63;
        const int half = lane >> 5, c32 = lane & 31;
        const int task  = bid * 4 + wave;        // 0..4095
        const int xtile = task & 255;            // 256 x-tiles of 32 x
        const int ysub  = (task >> 8) & 3;       // 4 y-subranges of 2048
        const int slot  = task >> 10;            // 0..3
        const int dir   = slot & 1;
        const int b     = slot >> 1;
        const int gX = dir*2 + b;
        const int gY = (1-dir)*2 + b;

        const short8* Abase = (const short8*)(ws + (half ? OFF_AFHI(gY) : OFF_AFLO(gY)));
        const short8* BR = (const short8*)(ws + OFF_BR(gX));
        const short8* BV = (const short8*)(ws + OFF_BV(gX));

        // 2 fused B-frags covering this wave's 32 x (cols n<16 raw, n>=16 vox)
        const int xbase = xtile * 32;
        S8 hc;
        hc.u[0] = (c32 < 16) ? (unsigned short)0 : (unsigned short)0x3F80;
        hc.u[1] = hc.u[0];
        hc.u[2]=0; hc.u[3]=0; hc.u[4]=0; hc.u[5]=0; hc.u[6]=0; hc.u[7]=0;
        const int xcol0 = xbase + (c32 & 15);
        const short8 bf0 = (half == 0) ? ((c32 < 16) ? BR[xcol0] : BV[xcol0]) : hc.v;
        const short8 bf1 = (half == 0) ? ((c32 < 16) ? BR[xcol0+16] : BV[xcol0+16]) : hc.v;

        float mn0 = INFINITY, mn1 = INFINITY;
        const f16v Z = (f16v)(0.0f);
        const int abase0 = ysub * 2048 + c32;

#pragma unroll 2
        for (int t = 0; t < 64; ++t) {           // 64 y-tiles of 32
            const short8 a = Abase[abase0 + t*32];
            const f16v d0 = __builtin_amdgcn_mfma_f32_32x32x16_bf16(a, bf0, Z, 0, 0, 0);
            {
                float t0 = fminf(fminf(d0[0], d0[1]),  fminf(d0[2], d0[3]));
                float t1 = fminf(fminf(d0[4], d0[5]),  fminf(d0[6], d0[7]));
                float t2 = fminf(fminf(d0[8], d0[9]),  fminf(d0[10], d0[11]));
                float t3 = fminf(fminf(d0[12], d0[13]), fminf(d0[14], d0[15]));
                mn0 = fminf(mn0, fminf(fminf(t0, t1), fminf(t2, t3)));
            }
            const f16v d1 = __builtin_amdgcn_mfma_f32_32x32x16_bf16(a, bf1, Z, 0, 0, 0);
            {
                float t0 = fminf(fminf(d1[0], d1[1]),  fminf(d1[2], d1[3]));
                float t1 = fminf(fminf(d1[4], d1[5]),  fminf(d1[6], d1[7]));
                float t2 = fminf(fminf(d1[8], d1[9]),  fminf(d1[10], d1[11]));
                float t3 = fminf(fminf(d1[12], d1[13]), fminf(d1[14], d1[15]));
                mn1 = fminf(mn1, fminf(fminf(t0, t1), fminf(t2, t3)));
            }
        }

        // other 16 rows live in the xor-32 partner lane (same column)
        mn0 = fminf(mn0, __shfl_xor(mn0, 32));
        mn1 = fminf(mn1, __shfl_xor(mn1, 32));

        if (half == 0) {
            // single writer per cell: plain coalesced stores, no init needed
            const int var = (c32 < 16) ? 0 : 1;
            ws[PART_IDX(ysub, slot, var, xcol0)]      = mn0;
            ws[PART_IDX(ysub, slot, var, xcol0 + 16)] = mn1;
        }
    }

    grid.sync();

    // ---------------- Phase C: finalize (blocks 0..127) ---------------------
    if (bid < 128) {
        const int g = bid * MBLK + tid;    // 0..32767 : one per (slot,x)
        const int slot = g >> 13;
        const int x    = g & (N-1);
        const int dir  = slot & 1;
        const int b    = slot >> 1;
        const int gX   = dir*2 + b;
        float m_r = INFINITY, m_v = INFINITY;
#pragma unroll
        for (int ys = 0; ys < 4; ++ys) {
            m_r = fminf(m_r, ws[PART_IDX(ys, slot, 0, x)]);
            m_v = fminf(m_v, ws[PART_IDX(ys, slot, 1, x)]);
        }
        float s = m_r + ws[OFF_XXR(gX) + x] + m_v + ws[OFF_XXV(gX) + x];
        for (int off = 32; off; off >>= 1)
            s += __shfl_down(s, off);
        __shared__ float sm[4];
        const int wave = tid >> 6, lane = tid & 63;
        if (lane == 0) sm[wave] = s;
        __syncthreads();
        if (tid == 0) {
            const float bs = sm[0] + sm[1] + sm[2] + sm[3];
            atomicAdd(ws + WS_ACC, bs);
            __threadfence();
            const unsigned t = atomicAdd(&((unsigned*)ws)[WS_TICKET], 1u);
            if (t == 127) {
                __threadfence();
                const float total = atomicAdd(ws + WS_ACC, 0.0f);  // atomic read
                out[0] = total * (1.0f / 16384.0f);
            }
        }
    }
}

extern "C" void kernel_launch(void* const* d_in, const int* in_sizes, int n_in,
                              void* d_out, int out_size, void* d_ws, size_t ws_size,
                              hipStream_t stream) {
    const float* preds = (const float*)d_in[0];
    const float* gts   = (const float*)d_in[1];
    float* ws  = (float*)d_ws;
    float* out = (float*)d_out;

    gmin_kernel<<<dim3(4), dim3(PBLK), 0, stream>>>(preds, gts, ws);

    void* args[] = { (void*)&preds, (void*)&gts, (void*)&ws, (void*)&out };
    hipLaunchCooperativeKernel((void*)mega_kernel, dim3(MGRID), dim3(MBLK),
                               args, 0, stream);
}

// Round 12
// 107.801 us; speedup vs baseline: 2.4073x; 2.4073x over previous
//
#include <hip/hip_runtime.h>
#include <math.h>

// Problem constants
#define B 2
#define N 8192            // points per batch
#define PTS_STRIDE (N*3)
#define VOXEL 0.1f

#define CBLK 128          // chamfer: 2 waves per block, no LDS, no barriers
#define PBLK 1024

// ws layout (float offsets); ws_size >= 17 MB known, we use ~4.3 MB.
//  [16] acc   [17] ticket   [20..31] gmin[g][3]
//  OFF_PACK per g=arr*2+b (PERG=147456 floats):
//    AFLO[N] short8: [y0,y1,y2,yyh,yyl,w0,w1,w2]   (A rows, k=0..7)
//    AFHI[N] short8: [vvh,vvl,0,...]               (A rows, k=8..15)
//    BR[N]   short8: [-2x0,-2x1,-2x2,1,1,0,0,0]    (B raw col, k=0..7)
//    BV[N]   short8: [0,0,0,0,0,-2u0,-2u1,-2u2]    (B vox col, k=0..7)
//    XXR[N], XXV[N] f32
//  OFF_PART: float part[ysub(8)][slot(4)][var(2)][x(8192)] = 2 MB, single writer per cell
#define WS_ACC 16
#define WS_TICKET 17
#define WS_GMIN 20
#define OFF_PACK 32
#define PERG 147456
#define OFF_AFLO(g) (OFF_PACK + (g)*PERG)
#define OFF_AFHI(g) (OFF_AFLO(g) + 32768)
#define OFF_BR(g)   (OFF_AFLO(g) + 65536)
#define OFF_BV(g)   (OFF_AFLO(g) + 98304)
#define OFF_XXR(g)  (OFF_AFLO(g) + 131072)
#define OFF_XXV(g)  (OFF_AFLO(g) + 139264)
#define OFF_PART    (OFF_PACK + 4*PERG)
#define PART_IDX(ys, slot, var, x) (OFF_PART + (((((ys)*4 + (slot))*2 + (var)) << 13)) + (x))

typedef __attribute__((ext_vector_type(8))) short short8;    // 8 bf16 (MFMA A/B frag)
typedef __attribute__((ext_vector_type(16))) float f16v;     // 32x32 MFMA C/D frag

union S8 { short8 v; unsigned short u[8]; };

__device__ __forceinline__ unsigned short f2bf(float f) {    // RNE f32->bf16
    unsigned u = __float_as_uint(f);
    return (unsigned short)((u + 0x7FFFu + ((u >> 16) & 1u)) >> 16);
}
__device__ __forceinline__ float bf2f(unsigned short h) {
    return __uint_as_float(((unsigned)h) << 16);
}
__device__ __forceinline__ float voxq(float v, float g) {
    return (float)(int)((v - g) / VOXEL);   // trunc like .astype(int32)
}

// 4 blocks (one per g=arr*2+b) x 1024: gmin reduce, then pack 8 points/thread.
__global__ void __launch_bounds__(PBLK)
prep_kernel(const float* __restrict__ preds,
            const float* __restrict__ gts,
            float* __restrict__ ws) {
    const int g   = blockIdx.x;
    const int arr = g >> 1;
    const int b   = g & 1;
    const float* base = (arr ? gts : preds) + b * PTS_STRIDE;
    const float4* base4 = (const float4*)base;

    // --- gmin (NaN -> inf), vectorized 3x float4 = 4 points per iter ---
    float m0 = INFINITY, m1 = INFINITY, m2 = INFINITY;
#pragma unroll
    for (int j = 0; j < 2; ++j) {
        const int i = j * PBLK + threadIdx.x;     // 0..2047, 4 points each
        const float4 q0 = base4[i*3+0];   // p0x p0y p0z p1x
        const float4 q1 = base4[i*3+1];   // p1y p1z p2x p2y
        const float4 q2 = base4[i*3+2];   // p2z p3x p3y p3z
        float v;
        v = q0.x; m0 = fminf(m0, (v!=v)?INFINITY:v);
        v = q0.w; m0 = fminf(m0, (v!=v)?INFINITY:v);
        v = q1.z; m0 = fminf(m0, (v!=v)?INFINITY:v);
        v = q2.y; m0 = fminf(m0, (v!=v)?INFINITY:v);
        v = q0.y; m1 = fminf(m1, (v!=v)?INFINITY:v);
        v = q1.x; m1 = fminf(m1, (v!=v)?INFINITY:v);
        v = q1.w; m1 = fminf(m1, (v!=v)?INFINITY:v);
        v = q2.z; m1 = fminf(m1, (v!=v)?INFINITY:v);
        v = q0.z; m2 = fminf(m2, (v!=v)?INFINITY:v);
        v = q1.y; m2 = fminf(m2, (v!=v)?INFINITY:v);
        v = q2.x; m2 = fminf(m2, (v!=v)?INFINITY:v);
        v = q2.w; m2 = fminf(m2, (v!=v)?INFINITY:v);
    }
    for (int off = 32; off; off >>= 1) {
        m0 = fminf(m0, __shfl_down(m0, off));
        m1 = fminf(m1, __shfl_down(m1, off));
        m2 = fminf(m2, __shfl_down(m2, off));
    }
    __shared__ float sm[16][3];
    __shared__ float gsh[3];
    const int wave = threadIdx.x >> 6, lane = threadIdx.x & 63;
    if (lane == 0) { sm[wave][0] = m0; sm[wave][1] = m1; sm[wave][2] = m2; }
    __syncthreads();
    if (threadIdx.x == 0) {
        float a0 = sm[0][0], a1 = sm[0][1], a2 = sm[0][2];
        for (int w = 1; w < 16; ++w) {
            a0 = fminf(a0, sm[w][0]);
            a1 = fminf(a1, sm[w][1]);
            a2 = fminf(a2, sm[w][2]);
        }
        ws[WS_GMIN + g*3+0] = a0; ws[WS_GMIN + g*3+1] = a1; ws[WS_GMIN + g*3+2] = a2;
        gsh[0] = a0; gsh[1] = a1; gsh[2] = a2;
        if (g == 0) { ws[WS_ACC] = 0.0f; ((unsigned*)ws)[WS_TICKET] = 0u; }
    }
    __syncthreads();
    const float g0 = gsh[0], g1 = gsh[1], g2 = gsh[2];

    // --- pack 8 points per thread (coalesced idx = k*1024 + tid) ---
    short8* AFLO = (short8*)(ws + OFF_AFLO(g));
    short8* AFHI = (short8*)(ws + OFF_AFHI(g));
    short8* BR   = (short8*)(ws + OFF_BR(g));
    short8* BV   = (short8*)(ws + OFF_BV(g));
    const unsigned short ONE = 0x3F80;

#pragma unroll 2
    for (int k = 0; k < 8; ++k) {
        const int idx = k * PBLK + threadIdx.x;
        const float p0 = base[idx*3+0], p1 = base[idx*3+1], p2 = base[idx*3+2];
        const float w0 = voxq(p0, g0), w1 = voxq(p1, g1), w2 = voxq(p2, g2);
        const float rr = fmaf(p0,p0, fmaf(p1,p1, p2*p2));
        const float vv = fmaf(w0,w0, fmaf(w1,w1, w2*w2));

        const unsigned short yyh = f2bf(rr);
        const unsigned short yyl = f2bf(rr - bf2f(yyh));
        const unsigned short vvh = f2bf(vv);
        const unsigned short vvl = f2bf(vv - bf2f(vvh));

        S8 f;
        // A lo (k=0..7): [y0,y1,y2,yyh,yyl, w0,w1,w2]
        f.u[0]=f2bf(p0); f.u[1]=f2bf(p1); f.u[2]=f2bf(p2);
        f.u[3]=yyh; f.u[4]=yyl; f.u[5]=f2bf(w0); f.u[6]=f2bf(w1); f.u[7]=f2bf(w2);
        AFLO[idx] = f.v;
        // A hi (k=8..15): [vvh,vvl,0...]
        f.u[0]=vvh; f.u[1]=vvl; f.u[2]=0; f.u[3]=0; f.u[4]=0; f.u[5]=0; f.u[6]=0; f.u[7]=0;
        AFHI[idx] = f.v;
        // B raw col (k=0..7)
        f.u[0]=f2bf(-2.0f*p0); f.u[1]=f2bf(-2.0f*p1); f.u[2]=f2bf(-2.0f*p2);
        f.u[3]=ONE; f.u[4]=ONE; f.u[5]=0; f.u[6]=0; f.u[7]=0;
        BR[idx] = f.v;
        // B vox col (k=0..7)
        f.u[0]=0; f.u[1]=0; f.u[2]=0; f.u[3]=0; f.u[4]=0;
        f.u[5]=f2bf(-2.0f*w0); f.u[6]=f2bf(-2.0f*w1); f.u[7]=f2bf(-2.0f*w2);
        BV[idx] = f.v;
        ws[OFF_XXR(g) + idx] = rr;
        ws[OFF_XXV(g) + idx] = vv;
    }
}

// Chamfer: 4096 blocks (256 xtiles x 4 ypairs x 4 slots) x 128 threads.
// 2 independent waves per block; wave w covers ysub = blockIdx.y*2+w (1024 y).
// Per wave: 2 fused B-frags (32 x; cols n<16 raw x_n, n>=16 vox x_{n-16}).
// A-frags straight from global (coalesced 16B/lane). No LDS, no barriers,
// no atomics: single-writer partial stores per (ysub,slot,var,x).
// 8 persistent v_min3 accumulators per chain: 16 min3/iter total.
__global__ void __launch_bounds__(CBLK, 5)
chamfer_kernel(float* __restrict__ ws) {
    const int tid  = threadIdx.x;
    const int wave = tid >> 6, lane = tid & 63;
    const int half = lane >> 5, c32 = lane & 31;
    const int slot = blockIdx.z;           // 0..3
    const int dir  = slot & 1;
    const int b    = slot >> 1;
    const int gX = dir*2 + b;
    const int gY = (1-dir)*2 + b;

    const short8* Abase = (const short8*)(ws + (half ? OFF_AFHI(gY) : OFF_AFLO(gY)));
    const short8* BR = (const short8*)(ws + OFF_BR(gX));
    const short8* BV = (const short8*)(ws + OFF_BV(gX));

    // 2 fused B-frags for this block's 32 x
    const int xbase = blockIdx.x * 32;
    S8 hc;
    hc.u[0] = (c32 < 16) ? (unsigned short)0 : (unsigned short)0x3F80;
    hc.u[1] = hc.u[0];
    hc.u[2]=0; hc.u[3]=0; hc.u[4]=0; hc.u[5]=0; hc.u[6]=0; hc.u[7]=0;
    const int xcol0 = xbase + (c32 & 15);
    const short8 bf0 = (half == 0) ? ((c32 < 16) ? BR[xcol0] : BV[xcol0]) : hc.v;
    const short8 bf1 = (half == 0) ? ((c32 < 16) ? BR[xcol0+16] : BV[xcol0+16]) : hc.v;

    float mA[8], mB[8];
#pragma unroll
    for (int r = 0; r < 8; ++r) { mA[r] = INFINITY; mB[r] = INFINITY; }

    const f16v Z = (f16v)(0.0f);
    const int ysub = blockIdx.y * 2 + wave;         // 0..7
    const int abase0 = ysub * 1024 + c32;

#pragma unroll 2
    for (int t = 0; t < 32; ++t) {                  // 32 y-tiles of 32
        const short8 a = Abase[abase0 + t*32];
        const f16v d0 = __builtin_amdgcn_mfma_f32_32x32x16_bf16(a, bf0, Z, 0, 0, 0);
        const f16v d1 = __builtin_amdgcn_mfma_f32_32x32x16_bf16(a, bf1, Z, 0, 0, 0);
#pragma unroll
        for (int r = 0; r < 8; ++r) {
            mA[r] = fminf(mA[r], fminf(d0[2*r], d0[2*r+1]));   // -> v_min3
            mB[r] = fminf(mB[r], fminf(d1[2*r], d1[2*r+1]));
        }
    }

    // fold 8 -> 1 per chain
    float mn0 = fminf(fminf(fminf(mA[0], mA[1]), fminf(mA[2], mA[3])),
                      fminf(fminf(mA[4], mA[5]), fminf(mA[6], mA[7])));
    float mn1 = fminf(fminf(fminf(mB[0], mB[1]), fminf(mB[2], mB[3])),
                      fminf(fminf(mB[4], mB[5]), fminf(mB[6], mB[7])));

    // other 16 rows live in the xor-32 partner lane (same column)
    mn0 = fminf(mn0, __shfl_xor(mn0, 32));
    mn1 = fminf(mn1, __shfl_xor(mn1, 32));

    if (half == 0) {
        // single writer per cell: plain coalesced stores, no init needed
        const int var = (c32 < 16) ? 0 : 1;
        ws[PART_IDX(ysub, slot, var, xcol0)]      = mn0;
        ws[PART_IDX(ysub, slot, var, xcol0 + 16)] = mn1;
    }
}

// 128 blocks x 256: one thread per (slot,x). Fold 8 ysubs, add |x|^2, sum, ticket-out.
__global__ void __launch_bounds__(256)
finalize_kernel(float* __restrict__ ws, float* __restrict__ out) {
    const int g = blockIdx.x * 256 + threadIdx.x;   // 0..32767
    const int slot = g >> 13;
    const int x    = g & (N-1);
    const int dir  = slot & 1;
    const int b    = slot >> 1;
    const int gX   = dir*2 + b;
    float m_r = INFINITY, m_v = INFINITY;
#pragma unroll
    for (int ys = 0; ys < 8; ++ys) {
        m_r = fminf(m_r, ws[PART_IDX(ys, slot, 0, x)]);
        m_v = fminf(m_v, ws[PART_IDX(ys, slot, 1, x)]);
    }
    float s = m_r + ws[OFF_XXR(gX) + x] + m_v + ws[OFF_XXV(gX) + x];
    for (int off = 32; off; off >>= 1)
        s += __shfl_down(s, off);
    __shared__ float sm[4];
    const int wave = threadIdx.x >> 6, lane = threadIdx.x & 63;
    if (lane == 0) sm[wave] = s;
    __syncthreads();
    if (threadIdx.x == 0) {
        const float bs = sm[0] + sm[1] + sm[2] + sm[3];
        atomicAdd(ws + WS_ACC, bs);
        __threadfence();
        const unsigned t = atomicAdd(&((unsigned*)ws)[WS_TICKET], 1u);
        if (t == gridDim.x - 1) {
            __threadfence();
            const float total = atomicAdd(ws + WS_ACC, 0.0f);  // atomic read
            out[0] = total * (1.0f / 16384.0f);
        }
    }
}

extern "C" void kernel_launch(void* const* d_in, const int* in_sizes, int n_in,
                              void* d_out, int out_size, void* d_ws, size_t ws_size,
                              hipStream_t stream) {
    const float* preds = (const float*)d_in[0];
    const float* gts   = (const float*)d_in[1];
    float* ws  = (float*)d_ws;
    float* out = (float*)d_out;

    prep_kernel<<<dim3(4), dim3(PBLK), 0, stream>>>(preds, gts, ws);
    chamfer_kernel<<<dim3(N/32, 4, 4), dim3(CBLK), 0, stream>>>(ws);
    finalize_kernel<<<dim3(128), dim3(256), 0, stream>>>(ws, out);
}